// Round 1
// baseline (479.423 us; speedup 1.0000x reference)
//
#include <hip/hip_runtime.h>
#include <math.h>

#define B_  2
#define CIN 64
#define COUT 64
#define H_  192
#define W_  192
#define G_  2
#define KK_ 9
#define CG_ 32
#define HW_ (H_*W_)

// ---------------------------------------------------------------------------
// Kernel 0: transpose weight (COUT,CIN,3,3) -> wt[g][k][c][o] contiguous in o
// ---------------------------------------------------------------------------
__global__ void wtrans_kernel(const float* __restrict__ weight,
                              float* __restrict__ wt) {
    int i = blockIdx.x * blockDim.x + threadIdx.x;
    if (i >= COUT * CIN * 9) return;
    int o = i % COUT;
    int c = (i / COUT) % CG_;
    int k = (i / (COUT * CG_)) % KK_;
    int g = i / (COUT * CG_ * KK_);
    wt[i] = weight[(o * CIN + g * CG_ + c) * 9 + k];
}

// ---------------------------------------------------------------------------
// Kernel 1: fused small convs -> py, px, dmask   (layout B,G,K,H,W)
// ---------------------------------------------------------------------------
__global__ void offsets_kernel(const float* __restrict__ input,
                               const float* __restrict__ mask_in,
                               const float* __restrict__ sem_w, const float* __restrict__ sem_b,
                               const float* __restrict__ reg_w, const float* __restrict__ reg_b,
                               const float* __restrict__ m1_w, const float* __restrict__ m1_b,
                               const float* __restrict__ m2_w, const float* __restrict__ m2_b,
                               float* __restrict__ py, float* __restrict__ px,
                               float* __restrict__ dmask) {
    int idx = blockIdx.x * blockDim.x + threadIdx.x;
    if (idx >= B_ * HW_) return;
    int x = idx % W_;
    int y = (idx / W_) % H_;
    int b = idx / HW_;

    // ---- mask-driven convs: reg (18 ch) and m1 (9 ch) ----
    float regacc[18], m1acc[9];
    #pragma unroll
    for (int o = 0; o < 18; ++o) regacc[o] = reg_b[o];
    #pragma unroll
    for (int o = 0; o < 9; ++o) m1acc[o] = m1_b[o];
    #pragma unroll
    for (int t = 0; t < 9; ++t) {
        int dy = t / 3 - 1, dx = t % 3 - 1;
        int yy = y + dy, xx = x + dx;
        float v = (yy >= 0 && yy < H_ && xx >= 0 && xx < W_)
                    ? mask_in[b * HW_ + yy * W_ + xx] : 0.f;
        #pragma unroll
        for (int o = 0; o < 18; ++o) regacc[o] += v * reg_w[o * 9 + t];
        #pragma unroll
        for (int o = 0; o < 9; ++o) m1acc[o] += v * m1_w[o * 9 + t];
    }

    // ---- input-driven convs: sem (18 ch) and m2 (9 ch) ----
    float semacc[18], m2acc[9];
    #pragma unroll
    for (int o = 0; o < 18; ++o) semacc[o] = sem_b[o];
    #pragma unroll
    for (int o = 0; o < 9; ++o) m2acc[o] = m2_b[o];
    for (int c = 0; c < CIN; ++c) {
        const float* ch = input + ((size_t)b * CIN + c) * HW_;
        float v[9];
        #pragma unroll
        for (int t = 0; t < 9; ++t) {
            int dy = t / 3 - 1, dx = t % 3 - 1;
            int yy = y + dy, xx = x + dx;
            v[t] = (yy >= 0 && yy < H_ && xx >= 0 && xx < W_)
                     ? ch[yy * W_ + xx] : 0.f;
        }
        #pragma unroll
        for (int t = 0; t < 9; ++t) {
            float vt = v[t];
            #pragma unroll
            for (int o = 0; o < 18; ++o) semacc[o] += vt * sem_w[(o * CIN + c) * 9 + t];
            #pragma unroll
            for (int o = 0; o < 9; ++o) m2acc[o] += vt * m2_w[(o * CIN + c) * 9 + t];
        }
    }

    // ---- emit py/px/dmask ----
    int pix = y * W_ + x;
    #pragma unroll
    for (int k = 0; k < 9; ++k) {
        float ky = (float)(k / 3 - 1), kx = (float)(k % 3 - 1);
        size_t o0 = ((size_t)(b * G_ + 0) * KK_ + k) * HW_ + pix;
        py[o0]    = regacc[2 * k]     + (float)y + ky;
        px[o0]    = regacc[2 * k + 1] + (float)x + kx;
        dmask[o0] = 1.f / (1.f + expf(-m1acc[k]));
        size_t o1 = ((size_t)(b * G_ + 1) * KK_ + k) * HW_ + pix;
        py[o1]    = semacc[2 * k]     + (float)y + ky;
        px[o1]    = semacc[2 * k + 1] + (float)x + kx;
        dmask[o1] = 1.f / (1.f + expf(-m2acc[k]));
    }
}

// ---------------------------------------------------------------------------
// Kernel 2: update_mask = clip(64 * sum_{g,k} bilin(mask, py, px), 0, 1)
// ---------------------------------------------------------------------------
__global__ void umask_kernel(const float* __restrict__ mask_in,
                             const float* __restrict__ py,
                             const float* __restrict__ px,
                             float* __restrict__ um_out) {
    int idx = blockIdx.x * blockDim.x + threadIdx.x;
    if (idx >= B_ * HW_) return;
    int x = idx % W_;
    int y = (idx / W_) % H_;
    int b = idx / HW_;
    int pix = y * W_ + x;

    const float* mb = mask_in + (size_t)b * HW_;
    float s = 0.f;
    for (int gk = 0; gk < G_ * KK_; ++gk) {
        size_t off = ((size_t)b * G_ * KK_ + gk) * HW_ + pix;
        float Y = py[off], X = px[off];
        float y0f = floorf(Y), x0f = floorf(X);
        int y0 = (int)y0f, x0 = (int)x0f;
        float ly = Y - y0f, lx = X - x0f;
        int y1 = y0 + 1, x1 = x0 + 1;
        bool vy0 = (y0 >= 0 && y0 < H_), vy1 = (y1 >= 0 && y1 < H_);
        bool vx0 = (x0 >= 0 && x0 < W_), vx1 = (x1 >= 0 && x1 < W_);
        int yc0 = min(max(y0, 0), H_ - 1), yc1 = min(max(y1, 0), H_ - 1);
        int xc0 = min(max(x0, 0), W_ - 1), xc1 = min(max(x1, 0), W_ - 1);
        float v00 = (vy0 && vx0) ? mb[yc0 * W_ + xc0] : 0.f;
        float v01 = (vy0 && vx1) ? mb[yc0 * W_ + xc1] : 0.f;
        float v10 = (vy1 && vx0) ? mb[yc1 * W_ + xc0] : 0.f;
        float v11 = (vy1 && vx1) ? mb[yc1 * W_ + xc1] : 0.f;
        s += v00 * (1.f - ly) * (1.f - lx) + v01 * (1.f - ly) * lx
           + v10 * ly * (1.f - lx)        + v11 * ly * lx;
    }
    float um = fminf(fmaxf(64.f * s, 0.f), 1.f);
    um_out[(size_t)b * HW_ + pix] = um;
}

// ---------------------------------------------------------------------------
// Kernel 3: main modulated deformable conv
//   out[b,o,y,x] = um * (bias[o] + sum_{g,k,c} bilin(in[b,g*32+c]) * dmask * w)
// ---------------------------------------------------------------------------
__global__ __launch_bounds__(256)
void main_kernel(const float* __restrict__ input,
                 const float* __restrict__ wt,     // [g][k][c][o]
                 const float* __restrict__ bias,
                 const float* __restrict__ py,
                 const float* __restrict__ px,
                 const float* __restrict__ dmask,
                 const float* __restrict__ um,
                 float* __restrict__ out) {
    int idx = blockIdx.x * blockDim.x + threadIdx.x;
    if (idx >= B_ * HW_) return;
    int x = idx % W_;
    int y = (idx / W_) % H_;
    int b = idx / HW_;
    int pix = y * W_ + x;

    float acc[COUT];
    #pragma unroll
    for (int o = 0; o < COUT; ++o) acc[o] = bias[o];

    for (int g = 0; g < G_; ++g) {
        const float* gbase = input + ((size_t)b * CIN + g * CG_) * HW_;
        for (int k = 0; k < KK_; ++k) {
            size_t off = (((size_t)b * G_ + g) * KK_ + k) * HW_ + pix;
            float Y = py[off], X = px[off], dm = dmask[off];
            float y0f = floorf(Y), x0f = floorf(X);
            int y0 = (int)y0f, x0 = (int)x0f;
            float ly = Y - y0f, lx = X - x0f;
            int y1 = y0 + 1, x1 = x0 + 1;
            bool vy0 = (y0 >= 0 && y0 < H_), vy1 = (y1 >= 0 && y1 < H_);
            bool vx0 = (x0 >= 0 && x0 < W_), vx1 = (x1 >= 0 && x1 < W_);
            float w00 = (vy0 && vx0) ? (1.f - ly) * (1.f - lx) * dm : 0.f;
            float w01 = (vy0 && vx1) ? (1.f - ly) * lx * dm : 0.f;
            float w10 = (vy1 && vx0) ? ly * (1.f - lx) * dm : 0.f;
            float w11 = (vy1 && vx1) ? ly * lx * dm : 0.f;
            int yc0 = min(max(y0, 0), H_ - 1), yc1 = min(max(y1, 0), H_ - 1);
            int xc0 = min(max(x0, 0), W_ - 1), xc1 = min(max(x1, 0), W_ - 1);
            int i00 = yc0 * W_ + xc0, i01 = yc0 * W_ + xc1;
            int i10 = yc1 * W_ + xc0, i11 = yc1 * W_ + xc1;

            const float* wgk = wt + (size_t)(g * KK_ + k) * CG_ * COUT;
            for (int c = 0; c < CG_; ++c) {
                const float* ch = gbase + (size_t)c * HW_;
                float s = w00 * ch[i00] + w01 * ch[i01]
                        + w10 * ch[i10] + w11 * ch[i11];
                const float* wrow = wgk + c * COUT;
                #pragma unroll
                for (int o = 0; o < COUT; ++o) acc[o] += s * wrow[o];
            }
        }
    }

    float u = um[(size_t)b * HW_ + pix];
    float* ob = out + (size_t)b * COUT * HW_ + pix;
    #pragma unroll
    for (int o = 0; o < COUT; ++o) ob[(size_t)o * HW_] = acc[o] * u;
}

// ---------------------------------------------------------------------------
extern "C" void kernel_launch(void* const* d_in, const int* in_sizes, int n_in,
                              void* d_out, int out_size, void* d_ws, size_t ws_size,
                              hipStream_t stream) {
    const float* input   = (const float*)d_in[0];
    const float* mask_in = (const float*)d_in[1];
    const float* weight  = (const float*)d_in[2];
    const float* bias    = (const float*)d_in[3];
    const float* sem_w   = (const float*)d_in[4];
    const float* sem_b   = (const float*)d_in[5];
    const float* reg_w   = (const float*)d_in[6];
    const float* reg_b   = (const float*)d_in[7];
    const float* m1_w    = (const float*)d_in[8];
    const float* m1_b    = (const float*)d_in[9];
    const float* m2_w    = (const float*)d_in[10];
    const float* m2_b    = (const float*)d_in[11];

    float* out = (float*)d_out;                        // (B,COUT,H,W)
    float* um  = out + (size_t)B_ * COUT * HW_;        // (B,1,H,W)

    // workspace layout (floats)
    const size_t n_gk = (size_t)B_ * G_ * KK_ * HW_;   // 1,327,104
    float* ws    = (float*)d_ws;
    float* py    = ws;
    float* px    = py + n_gk;
    float* dmask = px + n_gk;
    float* wt    = dmask + n_gk;                       // 36,864 floats

    const int npix = B_ * HW_;                         // 73,728
    const int blk = 256;

    wtrans_kernel<<<(COUT * CIN * 9 + blk - 1) / blk, blk, 0, stream>>>(weight, wt);
    offsets_kernel<<<(npix + blk - 1) / blk, blk, 0, stream>>>(
        input, mask_in, sem_w, sem_b, reg_w, reg_b, m1_w, m1_b, m2_w, m2_b,
        py, px, dmask);
    umask_kernel<<<(npix + blk - 1) / blk, blk, 0, stream>>>(mask_in, py, px, um);
    main_kernel<<<(npix + blk - 1) / blk, blk, 0, stream>>>(
        input, wt, bias, py, px, dmask, um, out);
}

// Round 2
// 300.063 us; speedup vs baseline: 1.5977x; 1.5977x over previous
//
#include <hip/hip_runtime.h>
#include <math.h>

#define B_  2
#define CIN 64
#define COUT 64
#define H_  192
#define W_  192
#define G_  2
#define KK_ 9
#define CG_ 32
#define HW_ (H_*W_)
#define PIX 64            // pixels per block (x-contiguous)
#define XT_ (W_/PIX)      // 3 x-tiles per row

// ---------------------------------------------------------------------------
// Kernel 0: build transposed weights.
//   wt [g][k][c][o]  (36864 floats)  : main conv, o contiguous for s_load_dwordx16
//   swt[c][t][32]    (18432 floats)  : o<18 -> sem_w[o][c][t], 18..26 -> m2_w[o-18][c][t]
// ---------------------------------------------------------------------------
__global__ void wtrans_kernel(const float* __restrict__ weight,
                              const float* __restrict__ sem_w,
                              const float* __restrict__ m2_w,
                              float* __restrict__ wt,
                              float* __restrict__ swt) {
    int i = blockIdx.x * blockDim.x + threadIdx.x;
    if (i < COUT * CIN * 9) {
        int o = i % COUT;
        int c = (i / COUT) % CG_;
        int k = (i / (COUT * CG_)) % KK_;
        int g = i / (COUT * CG_ * KK_);
        wt[i] = weight[(o * CIN + g * CG_ + c) * 9 + k];
        return;
    }
    int j = i - COUT * CIN * 9;
    if (j >= CIN * 9 * 32) return;
    int o = j % 32;
    int t = (j / 32) % 9;
    int c = j / 288;
    float v = 0.f;
    if (o < 18)      v = sem_w[(o * CIN + c) * 9 + t];
    else if (o < 27) v = m2_w[((o - 18) * CIN + c) * 9 + t];
    swt[j] = v;
}

// ---------------------------------------------------------------------------
// Kernel 1: fused offsets + modulation + update_mask.
//   Block: 64 pixels, 256 threads = 4 c-groups of 16 channels.
//   Phase 1: partial sem(18)+m2(9) conv sums over the group's 16 channels.
//   Phase 2: LDS reduce. Phase 3: wave0 (mask convs + group0 emit + um part),
//            wave1 (group1 emit + um part). Then um = clip(64*sum,0,1).
// ---------------------------------------------------------------------------
__global__ __launch_bounds__(256)
void offsets_kernel(const float* __restrict__ input,
                    const float* __restrict__ mask_in,
                    const float* __restrict__ swt,
                    const float* __restrict__ sem_b,
                    const float* __restrict__ reg_w, const float* __restrict__ reg_b,
                    const float* __restrict__ m1_w, const float* __restrict__ m1_b,
                    const float* __restrict__ m2_b,
                    float* __restrict__ py, float* __restrict__ px,
                    float* __restrict__ dmask, float* __restrict__ um_out) {
    __shared__ float part[27 * 4 * PIX];   // [o][grp][pix]
    __shared__ float red[27 * PIX];        // [o][pix]
    __shared__ float ums[2 * PIX];

    const int tid  = threadIdx.x;
    const int lane = tid & 63;
    const int grp  = __builtin_amdgcn_readfirstlane(tid >> 6);

    const int bid = blockIdx.x;
    const int xt = bid % XT_;
    const int y  = (bid / XT_) % H_;
    const int b  = bid / (XT_ * H_);
    const int x  = xt * PIX + lane;
    const int pix = y * W_ + x;

    // ---- phase 1: partial input convs over c in [grp*16, grp*16+16) ----
    float acc[27];
    #pragma unroll
    for (int o = 0; o < 27; ++o) acc[o] = 0.f;

    const bool vxm = (x - 1) >= 0, vxp = (x + 1) < W_;
    const bool vym = (y - 1) >= 0, vyp = (y + 1) < H_;

    for (int cc = 0; cc < 16; ++cc) {
        int c = grp * 16 + cc;
        const float* ch = input + ((size_t)b * CIN + c) * HW_ + pix;
        float v[9];
        v[0] = (vym && vxm) ? ch[-W_ - 1] : 0.f;
        v[1] = vym ? ch[-W_] : 0.f;
        v[2] = (vym && vxp) ? ch[-W_ + 1] : 0.f;
        v[3] = vxm ? ch[-1] : 0.f;
        v[4] = ch[0];
        v[5] = vxp ? ch[1] : 0.f;
        v[6] = (vyp && vxm) ? ch[W_ - 1] : 0.f;
        v[7] = vyp ? ch[W_] : 0.f;
        v[8] = (vyp && vxp) ? ch[W_ + 1] : 0.f;
        const float* wp = swt + (size_t)c * 9 * 32;
        #pragma unroll
        for (int t = 0; t < 9; ++t) {
            float vt = v[t];
            const float* w = wp + t * 32;
            #pragma unroll
            for (int o = 0; o < 27; ++o) acc[o] += vt * w[o];
        }
    }
    #pragma unroll
    for (int o = 0; o < 27; ++o) part[(o * 4 + grp) * PIX + lane] = acc[o];
    __syncthreads();

    // ---- phase 2: reduce 4 partials ----
    for (int i = tid; i < 27 * PIX; i += 256) {
        int base = (i >> 6) * (4 * PIX) + (i & 63);
        red[i] = part[base] + part[base + PIX] + part[base + 2 * PIX] + part[base + 3 * PIX];
    }
    __syncthreads();

    // ---- phase 3: finish ----
    if (grp < 2) {
        float offacc[18], macc[9];
        if (grp == 0) {
            // mask-driven convs: reg (18) + m1 (9)
            #pragma unroll
            for (int o = 0; o < 18; ++o) offacc[o] = reg_b[o];
            #pragma unroll
            for (int o = 0; o < 9; ++o) macc[o] = m1_b[o];
            const float* mb = mask_in + (size_t)b * HW_ + pix;
            float v[9];
            v[0] = (vym && vxm) ? mb[-W_ - 1] : 0.f;
            v[1] = vym ? mb[-W_] : 0.f;
            v[2] = (vym && vxp) ? mb[-W_ + 1] : 0.f;
            v[3] = vxm ? mb[-1] : 0.f;
            v[4] = mb[0];
            v[5] = vxp ? mb[1] : 0.f;
            v[6] = (vyp && vxm) ? mb[W_ - 1] : 0.f;
            v[7] = vyp ? mb[W_] : 0.f;
            v[8] = (vyp && vxp) ? mb[W_ + 1] : 0.f;
            #pragma unroll
            for (int t = 0; t < 9; ++t) {
                float vt = v[t];
                #pragma unroll
                for (int o = 0; o < 18; ++o) offacc[o] += vt * reg_w[o * 9 + t];
                #pragma unroll
                for (int o = 0; o < 9; ++o) macc[o] += vt * m1_w[o * 9 + t];
            }
        } else {
            #pragma unroll
            for (int o = 0; o < 18; ++o) offacc[o] = red[o * PIX + lane] + sem_b[o];
            #pragma unroll
            for (int o = 0; o < 9; ++o) macc[o] = red[(18 + o) * PIX + lane] + m2_b[o];
        }

        const float* mb = mask_in + (size_t)b * HW_;
        float s_um = 0.f;
        #pragma unroll
        for (int k = 0; k < 9; ++k) {
            float Y = offacc[2 * k] + (float)y + (float)(k / 3 - 1);
            float X = offacc[2 * k + 1] + (float)x + (float)(k % 3 - 1);
            size_t off = (((size_t)b * G_ + grp) * KK_ + k) * HW_ + pix;
            py[off] = Y;
            px[off] = X;
            dmask[off] = 1.f / (1.f + expf(-macc[k]));
            // bilinear sample of mask for update_mask
            float y0f = floorf(Y), x0f = floorf(X);
            int y0 = (int)y0f, x0 = (int)x0f;
            float ly = Y - y0f, lx = X - x0f;
            int y1 = y0 + 1, x1 = x0 + 1;
            bool vy0 = (y0 >= 0 && y0 < H_), vy1 = (y1 >= 0 && y1 < H_);
            bool vx0 = (x0 >= 0 && x0 < W_), vx1 = (x1 >= 0 && x1 < W_);
            int yc0 = min(max(y0, 0), H_ - 1), yc1 = min(max(y1, 0), H_ - 1);
            int xc0 = min(max(x0, 0), W_ - 1), xc1 = min(max(x1, 0), W_ - 1);
            float v00 = (vy0 && vx0) ? mb[yc0 * W_ + xc0] : 0.f;
            float v01 = (vy0 && vx1) ? mb[yc0 * W_ + xc1] : 0.f;
            float v10 = (vy1 && vx0) ? mb[yc1 * W_ + xc0] : 0.f;
            float v11 = (vy1 && vx1) ? mb[yc1 * W_ + xc1] : 0.f;
            s_um += v00 * (1.f - ly) * (1.f - lx) + v01 * (1.f - ly) * lx
                  + v10 * ly * (1.f - lx)        + v11 * ly * lx;
        }
        ums[grp * PIX + lane] = s_um;
    }
    __syncthreads();
    if (grp == 0) {
        float um = fminf(fmaxf(64.f * (ums[lane] + ums[PIX + lane]), 0.f), 1.f);
        um_out[(size_t)b * HW_ + pix] = um;
    }
}

// ---------------------------------------------------------------------------
// Kernel 2: main modulated deformable conv.
//   Block: 64 pixels, 4 o-groups of 16. Per (g,k): cooperative gather of the
//   32-channel sampled tile into LDS (thread = (pixel, 8-channel slice)),
//   then each wave does the 32xK GEMM-let with uniform s_load weights.
// ---------------------------------------------------------------------------
__global__ __launch_bounds__(256)
void main_kernel(const float* __restrict__ input,
                 const float* __restrict__ wt,     // [g][k][c][o]
                 const float* __restrict__ bias,
                 const float* __restrict__ py,
                 const float* __restrict__ px,
                 const float* __restrict__ dmask,
                 const float* __restrict__ um,
                 float* __restrict__ out) {
    __shared__ float smp[CG_ * PIX];   // [c][pix]

    const int tid  = threadIdx.x;
    const int lane = tid & 63;
    const int grp  = __builtin_amdgcn_readfirstlane(tid >> 6);

    const int bid = blockIdx.x;
    const int xt = bid % XT_;
    const int y  = (bid / XT_) % H_;
    const int b  = bid / (XT_ * H_);
    const int x  = xt * PIX + lane;
    const int pix = y * W_ + x;

    float acc[16];
    #pragma unroll
    for (int o = 0; o < 16; ++o) acc[o] = bias[grp * 16 + o];

    for (int gk = 0; gk < G_ * KK_; ++gk) {
        int g = gk / KK_;
        // bilinear setup for this thread's pixel
        size_t off = ((size_t)b * G_ * KK_ + gk) * HW_ + pix;
        float Y = py[off], X = px[off], dm = dmask[off];
        float y0f = floorf(Y), x0f = floorf(X);
        int y0 = (int)y0f, x0 = (int)x0f;
        float ly = Y - y0f, lx = X - x0f;
        int y1 = y0 + 1, x1 = x0 + 1;
        bool vy0 = (y0 >= 0 && y0 < H_), vy1 = (y1 >= 0 && y1 < H_);
        bool vx0 = (x0 >= 0 && x0 < W_), vx1 = (x1 >= 0 && x1 < W_);
        float w00 = (vy0 && vx0) ? (1.f - ly) * (1.f - lx) * dm : 0.f;
        float w01 = (vy0 && vx1) ? (1.f - ly) * lx * dm : 0.f;
        float w10 = (vy1 && vx0) ? ly * (1.f - lx) * dm : 0.f;
        float w11 = (vy1 && vx1) ? ly * lx * dm : 0.f;
        int yc0 = min(max(y0, 0), H_ - 1), yc1 = min(max(y1, 0), H_ - 1);
        int xc0 = min(max(x0, 0), W_ - 1), xc1 = min(max(x1, 0), W_ - 1);
        int i00 = yc0 * W_ + xc0, i01 = yc0 * W_ + xc1;
        int i10 = yc1 * W_ + xc0, i11 = yc1 * W_ + xc1;

        // gather 8 channels for this pixel into LDS
        const float* chp = input + ((size_t)b * CIN + g * CG_ + grp * 8) * HW_;
        #pragma unroll
        for (int j = 0; j < 8; ++j) {
            float s = w00 * chp[i00] + w01 * chp[i01]
                    + w10 * chp[i10] + w11 * chp[i11];
            smp[(grp * 8 + j) * PIX + lane] = s;
            chp += HW_;
        }
        __syncthreads();

        // GEMM-let: 32 channels x 16 outputs
        const float* wbase = wt + ((size_t)gk * CG_) * COUT + grp * 16;
        #pragma unroll
        for (int c = 0; c < CG_; ++c) {
            float s = smp[c * PIX + lane];
            const float* wr = wbase + c * COUT;
            #pragma unroll
            for (int o = 0; o < 16; ++o) acc[o] += s * wr[o];
        }
        __syncthreads();
    }

    float u = um[(size_t)b * HW_ + pix];
    float* ob = out + ((size_t)b * COUT + grp * 16) * HW_ + pix;
    #pragma unroll
    for (int o = 0; o < 16; ++o) ob[(size_t)o * HW_] = acc[o] * u;
}

// ---------------------------------------------------------------------------
extern "C" void kernel_launch(void* const* d_in, const int* in_sizes, int n_in,
                              void* d_out, int out_size, void* d_ws, size_t ws_size,
                              hipStream_t stream) {
    const float* input   = (const float*)d_in[0];
    const float* mask_in = (const float*)d_in[1];
    const float* weight  = (const float*)d_in[2];
    const float* bias    = (const float*)d_in[3];
    const float* sem_w   = (const float*)d_in[4];
    const float* sem_b   = (const float*)d_in[5];
    const float* reg_w   = (const float*)d_in[6];
    const float* reg_b   = (const float*)d_in[7];
    const float* m1_w    = (const float*)d_in[8];
    const float* m1_b    = (const float*)d_in[9];
    const float* m2_w    = (const float*)d_in[10];
    const float* m2_b    = (const float*)d_in[11];

    float* out = (float*)d_out;                        // (B,COUT,H,W)
    float* um  = out + (size_t)B_ * COUT * HW_;        // (B,1,H,W)

    // workspace layout (floats)
    const size_t n_gk = (size_t)B_ * G_ * KK_ * HW_;   // 1,327,104
    float* ws    = (float*)d_ws;
    float* py    = ws;
    float* px    = py + n_gk;
    float* dmask = px + n_gk;
    float* wt    = dmask + n_gk;                       // 36,864 floats
    float* swt   = wt + (size_t)COUT * CIN * 9;        // 18,432 floats

    const int blk = 256;
    const int nblocks = B_ * H_ * XT_;                 // 1152

    wtrans_kernel<<<(COUT * CIN * 9 + CIN * 9 * 32 + blk - 1) / blk, blk, 0, stream>>>(
        weight, sem_w, m2_w, wt, swt);
    offsets_kernel<<<nblocks, blk, 0, stream>>>(
        input, mask_in, swt, sem_b, reg_w, reg_b, m1_w, m1_b, m2_b,
        py, px, dmask, um);
    main_kernel<<<nblocks, blk, 0, stream>>>(
        input, wt, bias, py, px, dmask, um, out);
}

// Round 4
// 254.991 us; speedup vs baseline: 1.8802x; 1.1768x over previous
//
#include <hip/hip_runtime.h>
#include <math.h>

#define B_  2
#define CIN 64
#define COUT 64
#define H_  192
#define W_  192
#define G_  2
#define KK_ 9
#define CG_ 32
#define HW_ (H_*W_)
#define PIX 64            // pixels per block (x-contiguous)
#define XT_ (W_/PIX)      // 3 x-tiles per row

typedef __attribute__((ext_vector_type(8))) short bf16x8;
typedef __attribute__((ext_vector_type(4))) float f32x4;

// round-to-nearest-even fp32 -> bf16 bit pattern
static __device__ __forceinline__ short f2bf(float f) {
    unsigned u = __builtin_bit_cast(unsigned, f);
    u = (u + 0x7fffu + ((u >> 16) & 1u)) >> 16;
    return (short)u;
}

// ---------------------------------------------------------------------------
// Kernel 0: build weights.
//  wt [g][k][c][o] (float, 36864) : main conv (scalar main kernel, round-2)
//  wbs[s(18)][nt(2)][lane][j] (bf16): sem(18)+m2(9)+pad, s = t*2+h,
//      o = nt*16 + (lane&15), c = h*32 + (lane>>4)*8 + j
// ---------------------------------------------------------------------------
__global__ void wtrans_kernel(const float* __restrict__ weight,
                              const float* __restrict__ sem_w,
                              const float* __restrict__ m2_w,
                              float* __restrict__ wt,
                              short* __restrict__ wbs) {
    int i = blockIdx.x * blockDim.x + threadIdx.x;
    if (i < COUT * CIN * 9) {
        int o = i % COUT;
        int c = (i / COUT) % CG_;
        int k = (i / (COUT * CG_)) % KK_;
        int g = i / (COUT * CG_ * KK_);
        wt[i] = weight[(o * CIN + g * CG_ + c) * 9 + k];
        return;
    }
    int ii = i - COUT * CIN * 9;
    if (ii >= 18 * 2 * 64 * 8) return;
    int j = ii & 7, lane = (ii >> 3) & 63, nt = (ii >> 9) & 1, s = ii >> 10;
    int t = s >> 1, h = s & 1;
    int n = lane & 15, q = lane >> 4;
    int o = nt * 16 + n;
    int c = h * 32 + q * 8 + j;
    float v = 0.f;
    if (o < 18)      v = sem_w[(o * CIN + c) * 9 + t];
    else if (o < 27) v = m2_w[((o - 18) * CIN + c) * 9 + t];
    wbs[ii] = f2bf(v);
}

// ---------------------------------------------------------------------------
// Kernel 1: offsets via MFMA im2col GEMM + scalar mask convs + fused umask.
//   (verbatim round-3 version — under test)
// ---------------------------------------------------------------------------
__global__ __launch_bounds__(256)
void offsets_kernel(const float* __restrict__ input,
                    const float* __restrict__ mask_in,
                    const short* __restrict__ wbs,
                    const float* __restrict__ sem_b,
                    const float* __restrict__ reg_w, const float* __restrict__ reg_b,
                    const float* __restrict__ m1_w, const float* __restrict__ m1_b,
                    const float* __restrict__ m2_b,
                    float* __restrict__ py, float* __restrict__ px,
                    float* __restrict__ dmask, float* __restrict__ um_out) {
    __shared__ __align__(16) short abuf[4 * 64 * 8];   // [quad][px][8] bf16
    __shared__ float red[64 * 36];                     // [px][o], pad 36
    __shared__ float ums[4 * 64];

    const int tid  = threadIdx.x;
    const int lane = tid & 63;
    const int w    = __builtin_amdgcn_readfirstlane(tid >> 6);

    const int bid = blockIdx.x;
    const int xt = bid % XT_;
    const int y  = (bid / XT_) % H_;
    const int b  = bid / (XT_ * H_);
    const int x  = xt * PIX + lane;
    const int pix = y * W_ + x;

    const bool vxm = x > 0, vxp = (x + 1) < W_;
    const bool vym = y > 0, vyp = (y + 1) < H_;

    f32x4 acc0 = {0.f, 0.f, 0.f, 0.f}, acc1 = {0.f, 0.f, 0.f, 0.f};

    for (int s = 0; s < 18; ++s) {
        int t = s >> 1, h = s & 1;
        int dy = t / 3 - 1, dx = t % 3 - 1;
        bool vy = dy < 0 ? vym : (dy > 0 ? vyp : true);
        bool vx = dx < 0 ? vxm : (dx > 0 ? vxp : true);
        bool vv = vy && vx;
        const float* ip = input + ((size_t)b * CIN + h * 32 + w * 8) * HW_
                        + (pix + dy * W_ + dx);
        bf16x8 av;
        #pragma unroll
        for (int j = 0; j < 8; ++j) {
            float v = vv ? ip[(size_t)j * HW_] : 0.f;
            av[j] = f2bf(v);
        }
        *(bf16x8*)&abuf[(w * 64 + lane) * 8] = av;
        __syncthreads();
        bf16x8 a = *(const bf16x8*)&abuf[((lane >> 4) * 64 + w * 16 + (lane & 15)) * 8];
        bf16x8 b0 = ((const bf16x8*)wbs)[(s * 2 + 0) * 64 + lane];
        bf16x8 b1 = ((const bf16x8*)wbs)[(s * 2 + 1) * 64 + lane];
        acc0 = __builtin_amdgcn_mfma_f32_16x16x32_bf16(a, b0, acc0, 0, 0, 0);
        acc1 = __builtin_amdgcn_mfma_f32_16x16x32_bf16(a, b1, acc1, 0, 0, 0);
        __syncthreads();
    }

    // dump C tiles to red[px][o] (pad 36 -> conflict-free)
    {
        int n = lane & 15, q = lane >> 4;
        #pragma unroll
        for (int r = 0; r < 4; ++r) {
            red[(w * 16 + q * 4 + r) * 36 + n]      = acc0[r];
            red[(w * 16 + q * 4 + r) * 36 + 16 + n] = acc1[r];
        }
    }
    __syncthreads();

    // finish: waves 0,1 -> region group (scalar mask convs); 2,3 -> semantic
    {
        int g  = w >> 1;
        int k0 = (w & 1) ? 5 : 0;
        int k1 = (w & 1) ? 9 : 5;
        float off_[18], mm[9];
        if (g == 0) {
            const float* mbp = mask_in + (size_t)b * HW_ + pix;
            float mv[9];
            mv[0] = (vym && vxm) ? mbp[-W_ - 1] : 0.f;
            mv[1] = vym ? mbp[-W_] : 0.f;
            mv[2] = (vym && vxp) ? mbp[-W_ + 1] : 0.f;
            mv[3] = vxm ? mbp[-1] : 0.f;
            mv[4] = mbp[0];
            mv[5] = vxp ? mbp[1] : 0.f;
            mv[6] = (vyp && vxm) ? mbp[W_ - 1] : 0.f;
            mv[7] = vyp ? mbp[W_] : 0.f;
            mv[8] = (vyp && vxp) ? mbp[W_ + 1] : 0.f;
            #pragma unroll
            for (int o = 0; o < 18; ++o) off_[o] = reg_b[o];
            #pragma unroll
            for (int o = 0; o < 9; ++o) mm[o] = m1_b[o];
            #pragma unroll
            for (int t = 0; t < 9; ++t) {
                float vt = mv[t];
                #pragma unroll
                for (int o = 0; o < 18; ++o) off_[o] += vt * reg_w[o * 9 + t];
                #pragma unroll
                for (int o = 0; o < 9; ++o) mm[o] += vt * m1_w[o * 9 + t];
            }
        } else {
            #pragma unroll
            for (int o = 0; o < 18; ++o) off_[o] = red[lane * 36 + o] + sem_b[o];
            #pragma unroll
            for (int o = 0; o < 9; ++o) mm[o] = red[lane * 36 + 18 + o] + m2_b[o];
        }

        const float* mb = mask_in + (size_t)b * HW_;
        float s_um = 0.f;
        #pragma unroll
        for (int k = 0; k < 9; ++k) {
            if (k < k0 || k >= k1) continue;
            float Y = off_[2 * k]     + (float)y + (float)(k / 3 - 1);
            float X = off_[2 * k + 1] + (float)x + (float)(k % 3 - 1);
            size_t off = (((size_t)b * G_ + g) * KK_ + k) * HW_ + pix;
            py[off] = Y;
            px[off] = X;
            dmask[off] = 1.f / (1.f + expf(-mm[k]));
            float y0f = floorf(Y), x0f = floorf(X);
            int y0 = (int)y0f, x0 = (int)x0f;
            float ly = Y - y0f, lx = X - x0f;
            int y1 = y0 + 1, x1 = x0 + 1;
            bool vy0 = (y0 >= 0 && y0 < H_), vy1 = (y1 >= 0 && y1 < H_);
            bool vx0 = (x0 >= 0 && x0 < W_), vx1 = (x1 >= 0 && x1 < W_);
            int yc0 = min(max(y0, 0), H_ - 1), yc1 = min(max(y1, 0), H_ - 1);
            int xc0 = min(max(x0, 0), W_ - 1), xc1 = min(max(x1, 0), W_ - 1);
            float v00 = (vy0 && vx0) ? mb[yc0 * W_ + xc0] : 0.f;
            float v01 = (vy0 && vx1) ? mb[yc0 * W_ + xc1] : 0.f;
            float v10 = (vy1 && vx0) ? mb[yc1 * W_ + xc0] : 0.f;
            float v11 = (vy1 && vx1) ? mb[yc1 * W_ + xc1] : 0.f;
            s_um += v00 * (1.f - ly) * (1.f - lx) + v01 * (1.f - ly) * lx
                  + v10 * ly * (1.f - lx)        + v11 * ly * lx;
        }
        ums[w * 64 + lane] = s_um;
    }
    __syncthreads();
    if (w == 0) {
        float s = ums[lane] + ums[64 + lane] + ums[128 + lane] + ums[192 + lane];
        um_out[(size_t)b * HW_ + pix] = fminf(fmaxf(64.f * s, 0.f), 1.f);
    }
}

// ---------------------------------------------------------------------------
// Kernel 2: main modulated deformable conv — round-2 SCALAR version (known good).
// ---------------------------------------------------------------------------
__global__ __launch_bounds__(256)
void main_kernel(const float* __restrict__ input,
                 const float* __restrict__ wt,     // [g][k][c][o]
                 const float* __restrict__ bias,
                 const float* __restrict__ py,
                 const float* __restrict__ px,
                 const float* __restrict__ dmask,
                 const float* __restrict__ um,
                 float* __restrict__ out) {
    __shared__ float smp[CG_ * PIX];   // [c][pix]

    const int tid  = threadIdx.x;
    const int lane = tid & 63;
    const int grp  = __builtin_amdgcn_readfirstlane(tid >> 6);

    const int bid = blockIdx.x;
    const int xt = bid % XT_;
    const int y  = (bid / XT_) % H_;
    const int b  = bid / (XT_ * H_);
    const int x  = xt * PIX + lane;
    const int pix = y * W_ + x;

    float acc[16];
    #pragma unroll
    for (int o = 0; o < 16; ++o) acc[o] = bias[grp * 16 + o];

    for (int gk = 0; gk < G_ * KK_; ++gk) {
        int g = gk / KK_;
        size_t off = ((size_t)b * G_ * KK_ + gk) * HW_ + pix;
        float Y = py[off], X = px[off], dm = dmask[off];
        float y0f = floorf(Y), x0f = floorf(X);
        int y0 = (int)y0f, x0 = (int)x0f;
        float ly = Y - y0f, lx = X - x0f;
        int y1 = y0 + 1, x1 = x0 + 1;
        bool vy0 = (y0 >= 0 && y0 < H_), vy1 = (y1 >= 0 && y1 < H_);
        bool vx0 = (x0 >= 0 && x0 < W_), vx1 = (x1 >= 0 && x1 < W_);
        float w00 = (vy0 && vx0) ? (1.f - ly) * (1.f - lx) * dm : 0.f;
        float w01 = (vy0 && vx1) ? (1.f - ly) * lx * dm : 0.f;
        float w10 = (vy1 && vx0) ? ly * (1.f - lx) * dm : 0.f;
        float w11 = (vy1 && vx1) ? ly * lx * dm : 0.f;
        int yc0 = min(max(y0, 0), H_ - 1), yc1 = min(max(y1, 0), H_ - 1);
        int xc0 = min(max(x0, 0), W_ - 1), xc1 = min(max(x1, 0), W_ - 1);
        int i00 = yc0 * W_ + xc0, i01 = yc0 * W_ + xc1;
        int i10 = yc1 * W_ + xc0, i11 = yc1 * W_ + xc1;

        // gather 8 channels for this pixel into LDS
        const float* chp = input + ((size_t)b * CIN + g * CG_ + grp * 8) * HW_;
        #pragma unroll
        for (int j = 0; j < 8; ++j) {
            float s = w00 * chp[i00] + w01 * chp[i01]
                    + w10 * chp[i10] + w11 * chp[i11];
            smp[(grp * 8 + j) * PIX + lane] = s;
            chp += HW_;
        }
        __syncthreads();

        // GEMM-let: 32 channels x 16 outputs
        const float* wbase = wt + ((size_t)gk * CG_) * COUT + grp * 16;
        #pragma unroll
        for (int c = 0; c < CG_; ++c) {
            float s = smp[c * PIX + lane];
            const float* wr = wbase + c * COUT;
            #pragma unroll
            for (int o = 0; o < 16; ++o) acc[o] += s * wr[o];
        }
        __syncthreads();
    }

    float u = um[(size_t)b * HW_ + pix];
    float* ob = out + ((size_t)b * COUT + grp * 16) * HW_ + pix;
    #pragma unroll
    for (int o = 0; o < 16; ++o) ob[(size_t)o * HW_] = acc[o] * u;
}

// ---------------------------------------------------------------------------
extern "C" void kernel_launch(void* const* d_in, const int* in_sizes, int n_in,
                              void* d_out, int out_size, void* d_ws, size_t ws_size,
                              hipStream_t stream) {
    const float* input   = (const float*)d_in[0];
    const float* mask_in = (const float*)d_in[1];
    const float* weight  = (const float*)d_in[2];
    const float* bias    = (const float*)d_in[3];
    const float* sem_w   = (const float*)d_in[4];
    const float* sem_b   = (const float*)d_in[5];
    const float* reg_w   = (const float*)d_in[6];
    const float* reg_b   = (const float*)d_in[7];
    const float* m1_w    = (const float*)d_in[8];
    const float* m1_b    = (const float*)d_in[9];
    const float* m2_w    = (const float*)d_in[10];
    const float* m2_b    = (const float*)d_in[11];

    float* out = (float*)d_out;                        // (B,COUT,H,W)
    float* um  = out + (size_t)B_ * COUT * HW_;        // (B,1,H,W)

    // workspace layout
    const size_t n_gk = (size_t)B_ * G_ * KK_ * HW_;   // 1,327,104
    float* ws    = (float*)d_ws;
    float* py    = ws;
    float* px    = py + n_gk;
    float* dmask = px + n_gk;
    float* wt    = dmask + n_gk;                       // 36,864 floats
    short* wbs   = (short*)(wt + (size_t)COUT * CIN * 9);  // 18,432 bf16

    const int blk = 256;
    const int nblocks = B_ * H_ * XT_;                 // 1152

    wtrans_kernel<<<(COUT * CIN * 9 + 18 * 2 * 64 * 8 + blk - 1) / blk, blk, 0, stream>>>(
        weight, sem_w, m2_w, wt, wbs);
    offsets_kernel<<<nblocks, blk, 0, stream>>>(
        input, mask_in, wbs, sem_b, reg_w, reg_b, m1_w, m1_b, m2_b,
        py, px, dmask, um);
    main_kernel<<<nblocks, blk, 0, stream>>>(
        input, wt, bias, py, px, dmask, um, out);
}

// Round 6
// 235.284 us; speedup vs baseline: 2.0376x; 1.0838x over previous
//
#include <hip/hip_runtime.h>
#include <math.h>

#define B_  2
#define CIN 64
#define COUT 64
#define H_  192
#define W_  192
#define G_  2
#define KK_ 9
#define CG_ 32
#define HW_ (H_*W_)
#define PIX 64            // pixels per block (x-contiguous)
#define XT_ (W_/PIX)      // 3 x-tiles per row

typedef __attribute__((ext_vector_type(8))) short bf16x8;
typedef __attribute__((ext_vector_type(4))) float f32x4;

// round-to-nearest-even fp32 -> bf16 bit pattern
static __device__ __forceinline__ short f2bf(float f) {
    unsigned u = __builtin_bit_cast(unsigned, f);
    u = (u + 0x7fffu + ((u >> 16) & 1u)) >> 16;
    return (short)u;
}

// ---------------------------------------------------------------------------
// Kernel 0: pack weights into MFMA B-fragment order (bf16).
//  wbm[gk][nt(4)][lane(64)][j(8)] : main conv,
//      o = nt*16 + (lane&15), cin = g*32 + (lane>>4)*8 + j, tap k (gk = g*9+k)
//  wbs[s(18)][nt(2)][lane][j]     : sem(18)+m2(9)+pad, s = t*2+h,
//      c = h*32 + (lane>>4)*8 + j
// ---------------------------------------------------------------------------
__global__ void wtrans_kernel(const float* __restrict__ weight,
                              const float* __restrict__ sem_w,
                              const float* __restrict__ m2_w,
                              short* __restrict__ wbm,
                              short* __restrict__ wbs) {
    int i = blockIdx.x * blockDim.x + threadIdx.x;
    if (i < 18 * 4 * 64 * 8) {
        int j = i & 7, lane = (i >> 3) & 63, nt = (i >> 9) & 3, gk = i >> 11;
        int n = lane & 15, q = lane >> 4;
        int o = nt * 16 + n;
        int g = gk / 9, k = gk - g * 9;
        int cin = g * CG_ + q * 8 + j;
        wbm[i] = f2bf(weight[(o * CIN + cin) * 9 + k]);
        return;
    }
    int ii = i - 18 * 4 * 64 * 8;
    if (ii >= 18 * 2 * 64 * 8) return;
    int j = ii & 7, lane = (ii >> 3) & 63, nt = (ii >> 9) & 1, s = ii >> 10;
    int t = s >> 1, h = s & 1;
    int n = lane & 15, q = lane >> 4;
    int o = nt * 16 + n;
    int c = h * 32 + q * 8 + j;
    float v = 0.f;
    if (o < 18)      v = sem_w[(o * CIN + c) * 9 + t];
    else if (o < 27) v = m2_w[((o - 18) * CIN + c) * 9 + t];
    wbs[ii] = f2bf(v);
}

// ---------------------------------------------------------------------------
// Kernel 1: offsets via MFMA im2col GEMM + scalar mask convs + fused umask.
//   (VERBATIM round-4 version — validated on HW, do not touch)
// ---------------------------------------------------------------------------
__global__ __launch_bounds__(256)
void offsets_kernel(const float* __restrict__ input,
                    const float* __restrict__ mask_in,
                    const short* __restrict__ wbs,
                    const float* __restrict__ sem_b,
                    const float* __restrict__ reg_w, const float* __restrict__ reg_b,
                    const float* __restrict__ m1_w, const float* __restrict__ m1_b,
                    const float* __restrict__ m2_b,
                    float* __restrict__ py, float* __restrict__ px,
                    float* __restrict__ dmask, float* __restrict__ um_out) {
    __shared__ __align__(16) short abuf[4 * 64 * 8];   // [quad][px][8] bf16
    __shared__ float red[64 * 36];                     // [px][o], pad 36
    __shared__ float ums[4 * 64];

    const int tid  = threadIdx.x;
    const int lane = tid & 63;
    const int w    = __builtin_amdgcn_readfirstlane(tid >> 6);

    const int bid = blockIdx.x;
    const int xt = bid % XT_;
    const int y  = (bid / XT_) % H_;
    const int b  = bid / (XT_ * H_);
    const int x  = xt * PIX + lane;
    const int pix = y * W_ + x;

    const bool vxm = x > 0, vxp = (x + 1) < W_;
    const bool vym = y > 0, vyp = (y + 1) < H_;

    f32x4 acc0 = {0.f, 0.f, 0.f, 0.f}, acc1 = {0.f, 0.f, 0.f, 0.f};

    for (int s = 0; s < 18; ++s) {
        int t = s >> 1, h = s & 1;
        int dy = t / 3 - 1, dx = t % 3 - 1;
        bool vy = dy < 0 ? vym : (dy > 0 ? vyp : true);
        bool vx = dx < 0 ? vxm : (dx > 0 ? vxp : true);
        bool vv = vy && vx;
        const float* ip = input + ((size_t)b * CIN + h * 32 + w * 8) * HW_
                        + (pix + dy * W_ + dx);
        bf16x8 av;
        #pragma unroll
        for (int j = 0; j < 8; ++j) {
            float v = vv ? ip[(size_t)j * HW_] : 0.f;
            av[j] = f2bf(v);
        }
        *(bf16x8*)&abuf[(w * 64 + lane) * 8] = av;
        __syncthreads();
        bf16x8 a = *(const bf16x8*)&abuf[((lane >> 4) * 64 + w * 16 + (lane & 15)) * 8];
        bf16x8 b0 = ((const bf16x8*)wbs)[(s * 2 + 0) * 64 + lane];
        bf16x8 b1 = ((const bf16x8*)wbs)[(s * 2 + 1) * 64 + lane];
        acc0 = __builtin_amdgcn_mfma_f32_16x16x32_bf16(a, b0, acc0, 0, 0, 0);
        acc1 = __builtin_amdgcn_mfma_f32_16x16x32_bf16(a, b1, acc1, 0, 0, 0);
        __syncthreads();
    }

    // dump C tiles to red[px][o] (pad 36 -> conflict-free)
    {
        int n = lane & 15, q = lane >> 4;
        #pragma unroll
        for (int r = 0; r < 4; ++r) {
            red[(w * 16 + q * 4 + r) * 36 + n]      = acc0[r];
            red[(w * 16 + q * 4 + r) * 36 + 16 + n] = acc1[r];
        }
    }
    __syncthreads();

    // finish: waves 0,1 -> region group (scalar mask convs); 2,3 -> semantic
    {
        int g  = w >> 1;
        int k0 = (w & 1) ? 5 : 0;
        int k1 = (w & 1) ? 9 : 5;
        float off_[18], mm[9];
        if (g == 0) {
            const float* mbp = mask_in + (size_t)b * HW_ + pix;
            float mv[9];
            mv[0] = (vym && vxm) ? mbp[-W_ - 1] : 0.f;
            mv[1] = vym ? mbp[-W_] : 0.f;
            mv[2] = (vym && vxp) ? mbp[-W_ + 1] : 0.f;
            mv[3] = vxm ? mbp[-1] : 0.f;
            mv[4] = mbp[0];
            mv[5] = vxp ? mbp[1] : 0.f;
            mv[6] = (vyp && vxm) ? mbp[W_ - 1] : 0.f;
            mv[7] = vyp ? mbp[W_] : 0.f;
            mv[8] = (vyp && vxp) ? mbp[W_ + 1] : 0.f;
            #pragma unroll
            for (int o = 0; o < 18; ++o) off_[o] = reg_b[o];
            #pragma unroll
            for (int o = 0; o < 9; ++o) mm[o] = m1_b[o];
            #pragma unroll
            for (int t = 0; t < 9; ++t) {
                float vt = mv[t];
                #pragma unroll
                for (int o = 0; o < 18; ++o) off_[o] += vt * reg_w[o * 9 + t];
                #pragma unroll
                for (int o = 0; o < 9; ++o) mm[o] += vt * m1_w[o * 9 + t];
            }
        } else {
            #pragma unroll
            for (int o = 0; o < 18; ++o) off_[o] = red[lane * 36 + o] + sem_b[o];
            #pragma unroll
            for (int o = 0; o < 9; ++o) mm[o] = red[lane * 36 + 18 + o] + m2_b[o];
        }

        const float* mb = mask_in + (size_t)b * HW_;
        float s_um = 0.f;
        #pragma unroll
        for (int k = 0; k < 9; ++k) {
            if (k < k0 || k >= k1) continue;
            float Y = off_[2 * k]     + (float)y + (float)(k / 3 - 1);
            float X = off_[2 * k + 1] + (float)x + (float)(k % 3 - 1);
            size_t off = (((size_t)b * G_ + g) * KK_ + k) * HW_ + pix;
            py[off] = Y;
            px[off] = X;
            dmask[off] = 1.f / (1.f + expf(-mm[k]));
            float y0f = floorf(Y), x0f = floorf(X);
            int y0 = (int)y0f, x0 = (int)x0f;
            float ly = Y - y0f, lx = X - x0f;
            int y1 = y0 + 1, x1 = x0 + 1;
            bool vy0 = (y0 >= 0 && y0 < H_), vy1 = (y1 >= 0 && y1 < H_);
            bool vx0 = (x0 >= 0 && x0 < W_), vx1 = (x1 >= 0 && x1 < W_);
            int yc0 = min(max(y0, 0), H_ - 1), yc1 = min(max(y1, 0), H_ - 1);
            int xc0 = min(max(x0, 0), W_ - 1), xc1 = min(max(x1, 0), W_ - 1);
            float v00 = (vy0 && vx0) ? mb[yc0 * W_ + xc0] : 0.f;
            float v01 = (vy0 && vx1) ? mb[yc0 * W_ + xc1] : 0.f;
            float v10 = (vy1 && vx0) ? mb[yc1 * W_ + xc0] : 0.f;
            float v11 = (vy1 && vx1) ? mb[yc1 * W_ + xc1] : 0.f;
            s_um += v00 * (1.f - ly) * (1.f - lx) + v01 * (1.f - ly) * lx
                  + v10 * ly * (1.f - lx)        + v11 * ly * lx;
        }
        ums[w * 64 + lane] = s_um;
    }
    __syncthreads();
    if (w == 0) {
        float s = ums[lane] + ums[64 + lane] + ums[128 + lane] + ums[192 + lane];
        um_out[(size_t)b * HW_ + pix] = fminf(fmaxf(64.f * s, 0.f), 1.f);
    }
}

// ---------------------------------------------------------------------------
// Kernel 2: main deformable conv via MFMA — direct per-thread fragment build,
//   accumulators as NAMED scalars (acc0..acc3), MFMAs hand-unrolled to match
//   the HW-verified offsets_kernel code shape exactly.
// ---------------------------------------------------------------------------
__global__ __launch_bounds__(256)
void main_kernel(const float* __restrict__ input,
                 const short* __restrict__ wbm,
                 const float* __restrict__ bias,
                 const float* __restrict__ py,
                 const float* __restrict__ px,
                 const float* __restrict__ dmask,
                 const float* __restrict__ um,
                 float* __restrict__ out) {
    __shared__ float dout[64 * 68];                    // [px][o], pad 68

    const int tid  = threadIdx.x;
    const int lane = tid & 63;
    const int w    = __builtin_amdgcn_readfirstlane(tid >> 6);
    const int n = lane & 15, q = lane >> 4;

    const int bid = blockIdx.x;
    const int xt = bid % XT_;
    const int y  = (bid / XT_) % H_;
    const int b  = bid / (XT_ * H_);

    // fragment pixel (this thread's M-row)
    const int xf   = xt * PIX + w * 16 + n;
    const int pixf = y * W_ + xf;

    f32x4 acc0 = {0.f, 0.f, 0.f, 0.f};
    f32x4 acc1 = {0.f, 0.f, 0.f, 0.f};
    f32x4 acc2 = {0.f, 0.f, 0.f, 0.f};
    f32x4 acc3 = {0.f, 0.f, 0.f, 0.f};

    for (int gk = 0; gk < G_ * KK_; ++gk) {
        int g = gk >= 9 ? 1 : 0;
        size_t off = ((size_t)b * G_ * KK_ + gk) * HW_ + pixf;
        float Y = py[off], X = px[off], dm = dmask[off];
        float y0f = floorf(Y), x0f = floorf(X);
        int y0 = (int)y0f, x0 = (int)x0f;
        float ly = Y - y0f, lx = X - x0f;
        int y1 = y0 + 1, x1 = x0 + 1;
        bool vy0 = (y0 >= 0 && y0 < H_), vy1 = (y1 >= 0 && y1 < H_);
        bool vx0 = (x0 >= 0 && x0 < W_), vx1 = (x1 >= 0 && x1 < W_);
        float w00 = (vy0 && vx0) ? (1.f - ly) * (1.f - lx) * dm : 0.f;
        float w01 = (vy0 && vx1) ? (1.f - ly) * lx * dm : 0.f;
        float w10 = (vy1 && vx0) ? ly * (1.f - lx) * dm : 0.f;
        float w11 = (vy1 && vx1) ? ly * lx * dm : 0.f;
        int yc0 = min(max(y0, 0), H_ - 1), yc1 = min(max(y1, 0), H_ - 1);
        int xc0 = min(max(x0, 0), W_ - 1), xc1 = min(max(x1, 0), W_ - 1);
        int i00 = yc0 * W_ + xc0, i01 = yc0 * W_ + xc1;
        int i10 = yc1 * W_ + xc0, i11 = yc1 * W_ + xc1;

        const float* chp = input + ((size_t)b * CIN + g * CG_ + q * 8) * HW_;
        bf16x8 a;
        #pragma unroll
        for (int j = 0; j < 8; ++j) {
            float s = w00 * chp[i00] + w01 * chp[i01]
                    + w10 * chp[i10] + w11 * chp[i11];
            a[j] = f2bf(s);
            chp += HW_;
        }

        bf16x8 b0 = ((const bf16x8*)wbm)[(gk * 4 + 0) * 64 + lane];
        bf16x8 b1 = ((const bf16x8*)wbm)[(gk * 4 + 1) * 64 + lane];
        bf16x8 b2 = ((const bf16x8*)wbm)[(gk * 4 + 2) * 64 + lane];
        bf16x8 b3 = ((const bf16x8*)wbm)[(gk * 4 + 3) * 64 + lane];
        acc0 = __builtin_amdgcn_mfma_f32_16x16x32_bf16(a, b0, acc0, 0, 0, 0);
        acc1 = __builtin_amdgcn_mfma_f32_16x16x32_bf16(a, b1, acc1, 0, 0, 0);
        acc2 = __builtin_amdgcn_mfma_f32_16x16x32_bf16(a, b2, acc2, 0, 0, 0);
        acc3 = __builtin_amdgcn_mfma_f32_16x16x32_bf16(a, b3, acc3, 0, 0, 0);
    }

    // epilogue: D -> LDS transpose -> coalesced stores (offsets-verified map)
    #pragma unroll
    for (int r = 0; r < 4; ++r) {
        dout[(w * 16 + q * 4 + r) * 68 +  0 + n] = acc0[r];
        dout[(w * 16 + q * 4 + r) * 68 + 16 + n] = acc1[r];
        dout[(w * 16 + q * 4 + r) * 68 + 32 + n] = acc2[r];
        dout[(w * 16 + q * 4 + r) * 68 + 48 + n] = acc3[r];
    }
    __syncthreads();

    const int x   = xt * PIX + lane;
    const int pix = y * W_ + x;
    float u = um[(size_t)b * HW_ + pix];
    float* ob = out + ((size_t)b * COUT + w * 16) * HW_ + pix;
    const float* bs = bias + w * 16;
    const float* dp = &dout[lane * 68 + w * 16];
    #pragma unroll
    for (int o = 0; o < 16; ++o)
        ob[(size_t)o * HW_] = (dp[o] + bs[o]) * u;
}

// ---------------------------------------------------------------------------
extern "C" void kernel_launch(void* const* d_in, const int* in_sizes, int n_in,
                              void* d_out, int out_size, void* d_ws, size_t ws_size,
                              hipStream_t stream) {
    const float* input   = (const float*)d_in[0];
    const float* mask_in = (const float*)d_in[1];
    const float* weight  = (const float*)d_in[2];
    const float* bias    = (const float*)d_in[3];
    const float* sem_w   = (const float*)d_in[4];
    const float* sem_b   = (const float*)d_in[5];
    const float* reg_w   = (const float*)d_in[6];
    const float* reg_b   = (const float*)d_in[7];
    const float* m1_w    = (const float*)d_in[8];
    const float* m1_b    = (const float*)d_in[9];
    const float* m2_w    = (const float*)d_in[10];
    const float* m2_b    = (const float*)d_in[11];

    float* out = (float*)d_out;                        // (B,COUT,H,W)
    float* um  = out + (size_t)B_ * COUT * HW_;        // (B,1,H,W)

    // workspace layout
    const size_t n_gk = (size_t)B_ * G_ * KK_ * HW_;   // 1,327,104
    float* ws    = (float*)d_ws;
    float* py    = ws;
    float* px    = py + n_gk;
    float* dmask = px + n_gk;
    short* wbm   = (short*)(dmask + n_gk);             // 36,864 bf16
    short* wbs   = wbm + 18 * 4 * 64 * 8;              // 18,432 bf16

    const int blk = 256;
    const int nblocks = B_ * H_ * XT_;                 // 1152

    wtrans_kernel<<<(18 * 4 * 64 * 8 + 18 * 2 * 64 * 8 + blk - 1) / blk, blk, 0, stream>>>(
        weight, sem_w, m2_w, wbm, wbs);
    offsets_kernel<<<nblocks, blk, 0, stream>>>(
        input, mask_in, wbs, sem_b, reg_w, reg_b, m1_w, m1_b, m2_b,
        py, px, dmask, um);
    main_kernel<<<nblocks, blk, 0, stream>>>(
        input, wbm, bias, py, px, dmask, um, out);
}

// Round 7
// 164.126 us; speedup vs baseline: 2.9211x; 1.4336x over previous
//
#include <hip/hip_runtime.h>
#include <math.h>

#define B_  2
#define CIN 64
#define COUT 64
#define H_  192
#define W_  192
#define G_  2
#define KK_ 9
#define CG_ 32
#define HW_ (H_*W_)
#define PIX 64            // pixels per block (x-contiguous)
#define XT_ (W_/PIX)      // 3 x-tiles per row

typedef __attribute__((ext_vector_type(8))) short bf16x8;
typedef __attribute__((ext_vector_type(4))) float f32x4;

// round-to-nearest-even fp32 -> bf16 bit pattern
static __device__ __forceinline__ short f2bf(float f) {
    unsigned u = __builtin_bit_cast(unsigned, f);
    u = (u + 0x7fffu + ((u >> 16) & 1u)) >> 16;
    return (short)u;
}
static __device__ __forceinline__ float bf2f(short s) {
    unsigned u = ((unsigned)(unsigned short)s) << 16;
    return __builtin_bit_cast(float, u);
}

// ---------------------------------------------------------------------------
// Kernel A: NCHW fp32 -> NHWC bf16 transform (LDS tile transpose).
//   inpT[(b*HW + pix)*64 + c]
// ---------------------------------------------------------------------------
__global__ __launch_bounds__(256)
void nhwc_kernel(const float* __restrict__ in, short* __restrict__ inpT) {
    __shared__ float t[64][65];
    const int tid = threadIdx.x;
    const int bid = blockIdx.x;                 // B * (HW/64) = 1152
    const int b = bid / (HW_ / 64);
    const int pix0 = (bid % (HW_ / 64)) * 64;
    const float* src = in + (size_t)b * CIN * HW_ + pix0;
    const int c0 = (tid >> 6) * 16;
    const int p  = tid & 63;
    #pragma unroll
    for (int i = 0; i < 16; ++i)
        t[c0 + i][p] = src[(size_t)(c0 + i) * HW_ + p];
    __syncthreads();
    short* dst = inpT + ((size_t)b * HW_ + pix0) * 64;
    #pragma unroll
    for (int i = 0; i < 16; ++i) {
        int idx = i * 256 + tid;
        int pp = idx >> 6, cc = idx & 63;
        dst[pp * 64 + cc] = f2bf(t[cc][pp]);
    }
}

// ---------------------------------------------------------------------------
// Kernel B: pack weights into MFMA B-fragment order (bf16). (r6-verified)
//  wbm[gk][nt(4)][lane(64)][j(8)] : o = nt*16+(lane&15), cin = g*32+(lane>>4)*8+j
//  wbs[s(18)][nt(2)][lane][j]     : s = t*2+h, c = h*32+(lane>>4)*8+j
// ---------------------------------------------------------------------------
__global__ void wtrans_kernel(const float* __restrict__ weight,
                              const float* __restrict__ sem_w,
                              const float* __restrict__ m2_w,
                              short* __restrict__ wbm,
                              short* __restrict__ wbs) {
    int i = blockIdx.x * blockDim.x + threadIdx.x;
    if (i < 18 * 4 * 64 * 8) {
        int j = i & 7, lane = (i >> 3) & 63, nt = (i >> 9) & 3, gk = i >> 11;
        int n = lane & 15, q = lane >> 4;
        int o = nt * 16 + n;
        int g = gk / 9, k = gk - g * 9;
        int cin = g * CG_ + q * 8 + j;
        wbm[i] = f2bf(weight[(o * CIN + cin) * 9 + k]);
        return;
    }
    int ii = i - 18 * 4 * 64 * 8;
    if (ii >= 18 * 2 * 64 * 8) return;
    int j = ii & 7, lane = (ii >> 3) & 63, nt = (ii >> 9) & 1, s = ii >> 10;
    int t = s >> 1, h = s & 1;
    int n = lane & 15, q = lane >> 4;
    int o = nt * 16 + n;
    int c = h * 32 + q * 8 + j;
    float v = 0.f;
    if (o < 18)      v = sem_w[(o * CIN + c) * 9 + t];
    else if (o < 27) v = m2_w[((o - 18) * CIN + c) * 9 + t];
    wbs[ii] = f2bf(v);
}

// ---------------------------------------------------------------------------
// Kernel C: fully fused — offsets (MFMA, direct A) + modulation + umask +
//           main deformable conv (MFMA, direct A). Offsets never leave LDS.
// ---------------------------------------------------------------------------
__global__ __launch_bounds__(256)
void fused_kernel(const short* __restrict__ inpT,
                  const float* __restrict__ mask_in,
                  const short* __restrict__ wbs,
                  const short* __restrict__ wbm,
                  const float* __restrict__ sem_b,
                  const float* __restrict__ reg_w, const float* __restrict__ reg_b,
                  const float* __restrict__ m1_w, const float* __restrict__ m1_b,
                  const float* __restrict__ m2_b,
                  const float* __restrict__ bias,
                  float* __restrict__ out, float* __restrict__ um_out) {
    // phase O/3: red [64][36] (9216 B) + ums [4][64] (1024 B)
    // phase M epilogue: dout [64][68] (17408 B) — overlaps red+ums (dead by then)
    __shared__ __align__(16) char sh[17408];
    float* red  = (float*)sh;
    float* ums  = (float*)(sh + 9216);
    float* dout = (float*)sh;
    __shared__ float pyl[18 * 64], pxl[18 * 64], dml[18 * 64];
    __shared__ float umv[64];

    const int tid  = threadIdx.x;
    const int lane = tid & 63;
    const int w    = __builtin_amdgcn_readfirstlane(tid >> 6);
    const int n = lane & 15, q = lane >> 4;

    const int bid = blockIdx.x;
    const int xt = bid % XT_;
    const int y  = (bid / XT_) % H_;
    const int b  = bid / (XT_ * H_);

    const int xn = xt * PIX + w * 16 + n;      // fragment pixel (M-row)

    // ================= phase O: sem(18)+m2(9) conv via MFMA =================
    f32x4 acc0 = {0.f, 0.f, 0.f, 0.f}, acc1 = {0.f, 0.f, 0.f, 0.f};
    for (int s = 0; s < 18; ++s) {
        int t_ = s >> 1, h = s & 1;
        int dy = t_ / 3 - 1, dx = t_ % 3 - 1;
        int yy = y + dy, xx = xn + dx;
        bool vv = (yy >= 0 && yy < H_ && xx >= 0 && xx < W_);
        int yc = min(max(yy, 0), H_ - 1), xc = min(max(xx, 0), W_ - 1);
        bf16x8 a = *(const bf16x8*)&inpT[((size_t)(b * HW_ + yc * W_ + xc)) * 64 + h * 32 + q * 8];
        if (!vv) { a[0]=0;a[1]=0;a[2]=0;a[3]=0;a[4]=0;a[5]=0;a[6]=0;a[7]=0; }
        bf16x8 b0 = ((const bf16x8*)wbs)[(s * 2 + 0) * 64 + lane];
        bf16x8 b1 = ((const bf16x8*)wbs)[(s * 2 + 1) * 64 + lane];
        acc0 = __builtin_amdgcn_mfma_f32_16x16x32_bf16(a, b0, acc0, 0, 0, 0);
        acc1 = __builtin_amdgcn_mfma_f32_16x16x32_bf16(a, b1, acc1, 0, 0, 0);
    }
    // dump C tiles to red[px][o] (pad 36)
    #pragma unroll
    for (int r = 0; r < 4; ++r) {
        red[(w * 16 + q * 4 + r) * 36 + n]      = acc0[r];
        red[(w * 16 + q * 4 + r) * 36 + 16 + n] = acc1[r];
    }
    __syncthreads();   // B1

    // ================= phase 3: finish offsets/modulation/umask =============
    {
        const int xl = xt * PIX + lane;        // this thread's pixel
        const int pixl = y * W_ + xl;
        const bool vxm = xl > 0, vxp = (xl + 1) < W_;
        const bool vym = y > 0,  vyp = (y + 1) < H_;
        int g  = w >> 1;
        int k0 = (w & 1) ? 5 : 0;
        int k1 = (w & 1) ? 9 : 5;
        float off_[18], mm[9];
        if (g == 0) {
            const float* mbp = mask_in + (size_t)b * HW_ + pixl;
            float mv[9];
            mv[0] = (vym && vxm) ? mbp[-W_ - 1] : 0.f;
            mv[1] = vym ? mbp[-W_] : 0.f;
            mv[2] = (vym && vxp) ? mbp[-W_ + 1] : 0.f;
            mv[3] = vxm ? mbp[-1] : 0.f;
            mv[4] = mbp[0];
            mv[5] = vxp ? mbp[1] : 0.f;
            mv[6] = (vyp && vxm) ? mbp[W_ - 1] : 0.f;
            mv[7] = vyp ? mbp[W_] : 0.f;
            mv[8] = (vyp && vxp) ? mbp[W_ + 1] : 0.f;
            #pragma unroll
            for (int o = 0; o < 18; ++o) off_[o] = reg_b[o];
            #pragma unroll
            for (int o = 0; o < 9; ++o) mm[o] = m1_b[o];
            #pragma unroll
            for (int t = 0; t < 9; ++t) {
                float vt = mv[t];
                #pragma unroll
                for (int o = 0; o < 18; ++o) off_[o] += vt * reg_w[o * 9 + t];
                #pragma unroll
                for (int o = 0; o < 9; ++o) mm[o] += vt * m1_w[o * 9 + t];
            }
        } else {
            #pragma unroll
            for (int o = 0; o < 18; ++o) off_[o] = red[lane * 36 + o] + sem_b[o];
            #pragma unroll
            for (int o = 0; o < 9; ++o) mm[o] = red[lane * 36 + 18 + o] + m2_b[o];
        }

        const float* mb = mask_in + (size_t)b * HW_;
        float s_um = 0.f;
        #pragma unroll
        for (int k = 0; k < 9; ++k) {
            if (k < k0 || k >= k1) continue;
            float Y = off_[2 * k]     + (float)y  + (float)(k / 3 - 1);
            float X = off_[2 * k + 1] + (float)xl + (float)(k % 3 - 1);
            int gk = g * 9 + k;
            pyl[gk * 64 + lane] = Y;
            pxl[gk * 64 + lane] = X;
            dml[gk * 64 + lane] = 1.f / (1.f + expf(-mm[k]));
            float y0f = floorf(Y), x0f = floorf(X);
            int y0 = (int)y0f, x0 = (int)x0f;
            float ly = Y - y0f, lx = X - x0f;
            int y1 = y0 + 1, x1 = x0 + 1;
            bool vy0 = (y0 >= 0 && y0 < H_), vy1 = (y1 >= 0 && y1 < H_);
            bool vx0 = (x0 >= 0 && x0 < W_), vx1 = (x1 >= 0 && x1 < W_);
            int yc0 = min(max(y0, 0), H_ - 1), yc1 = min(max(y1, 0), H_ - 1);
            int xc0 = min(max(x0, 0), W_ - 1), xc1 = min(max(x1, 0), W_ - 1);
            float v00 = (vy0 && vx0) ? mb[yc0 * W_ + xc0] : 0.f;
            float v01 = (vy0 && vx1) ? mb[yc0 * W_ + xc1] : 0.f;
            float v10 = (vy1 && vx0) ? mb[yc1 * W_ + xc0] : 0.f;
            float v11 = (vy1 && vx1) ? mb[yc1 * W_ + xc1] : 0.f;
            s_um += v00 * (1.f - ly) * (1.f - lx) + v01 * (1.f - ly) * lx
                  + v10 * ly * (1.f - lx)        + v11 * ly * lx;
        }
        ums[w * 64 + lane] = s_um;
    }
    __syncthreads();   // B2
    if (w == 0) {
        float s = ums[lane] + ums[64 + lane] + ums[128 + lane] + ums[192 + lane];
        float u = fminf(fmaxf(64.f * s, 0.f), 1.f);
        um_out[(size_t)b * HW_ + y * W_ + xt * PIX + lane] = u;
        umv[lane] = u;
    }
    __syncthreads();   // B3 (umv/ums safe before dout overlap)

    // ================= phase M: main deformable conv via MFMA ===============
    f32x4 macc0 = {0.f, 0.f, 0.f, 0.f};
    f32x4 macc1 = {0.f, 0.f, 0.f, 0.f};
    f32x4 macc2 = {0.f, 0.f, 0.f, 0.f};
    f32x4 macc3 = {0.f, 0.f, 0.f, 0.f};

    for (int gk = 0; gk < G_ * KK_; ++gk) {
        int g = gk >= 9 ? 1 : 0;
        float Y  = pyl[gk * 64 + w * 16 + n];
        float X  = pxl[gk * 64 + w * 16 + n];
        float dm = dml[gk * 64 + w * 16 + n];
        float y0f = floorf(Y), x0f = floorf(X);
        int y0 = (int)y0f, x0 = (int)x0f;
        float ly = Y - y0f, lx = X - x0f;
        int y1 = y0 + 1, x1 = x0 + 1;
        bool vy0 = (y0 >= 0 && y0 < H_), vy1 = (y1 >= 0 && y1 < H_);
        bool vx0 = (x0 >= 0 && x0 < W_), vx1 = (x1 >= 0 && x1 < W_);
        float w00 = (vy0 && vx0) ? (1.f - ly) * (1.f - lx) * dm : 0.f;
        float w01 = (vy0 && vx1) ? (1.f - ly) * lx * dm : 0.f;
        float w10 = (vy1 && vx0) ? ly * (1.f - lx) * dm : 0.f;
        float w11 = (vy1 && vx1) ? ly * lx * dm : 0.f;
        int yc0 = min(max(y0, 0), H_ - 1), yc1 = min(max(y1, 0), H_ - 1);
        int xc0 = min(max(x0, 0), W_ - 1), xc1 = min(max(x1, 0), W_ - 1);
        size_t pbase = (size_t)b * HW_;
        const short* p00 = inpT + ((pbase + yc0 * W_ + xc0) * 64 + g * CG_ + q * 8);
        const short* p01 = inpT + ((pbase + yc0 * W_ + xc1) * 64 + g * CG_ + q * 8);
        const short* p10 = inpT + ((pbase + yc1 * W_ + xc0) * 64 + g * CG_ + q * 8);
        const short* p11 = inpT + ((pbase + yc1 * W_ + xc1) * 64 + g * CG_ + q * 8);
        bf16x8 c00 = *(const bf16x8*)p00;
        bf16x8 c01 = *(const bf16x8*)p01;
        bf16x8 c10 = *(const bf16x8*)p10;
        bf16x8 c11 = *(const bf16x8*)p11;
        bf16x8 a;
        #pragma unroll
        for (int j = 0; j < 8; ++j) {
            float s = w00 * bf2f(c00[j]) + w01 * bf2f(c01[j])
                    + w10 * bf2f(c10[j]) + w11 * bf2f(c11[j]);
            a[j] = f2bf(s);
        }
        bf16x8 b0 = ((const bf16x8*)wbm)[(gk * 4 + 0) * 64 + lane];
        bf16x8 b1 = ((const bf16x8*)wbm)[(gk * 4 + 1) * 64 + lane];
        bf16x8 b2 = ((const bf16x8*)wbm)[(gk * 4 + 2) * 64 + lane];
        bf16x8 b3 = ((const bf16x8*)wbm)[(gk * 4 + 3) * 64 + lane];
        macc0 = __builtin_amdgcn_mfma_f32_16x16x32_bf16(a, b0, macc0, 0, 0, 0);
        macc1 = __builtin_amdgcn_mfma_f32_16x16x32_bf16(a, b1, macc1, 0, 0, 0);
        macc2 = __builtin_amdgcn_mfma_f32_16x16x32_bf16(a, b2, macc2, 0, 0, 0);
        macc3 = __builtin_amdgcn_mfma_f32_16x16x32_bf16(a, b3, macc3, 0, 0, 0);
    }

    // epilogue: D -> LDS transpose -> coalesced stores
    #pragma unroll
    for (int r = 0; r < 4; ++r) {
        dout[(w * 16 + q * 4 + r) * 68 +  0 + n] = macc0[r];
        dout[(w * 16 + q * 4 + r) * 68 + 16 + n] = macc1[r];
        dout[(w * 16 + q * 4 + r) * 68 + 32 + n] = macc2[r];
        dout[(w * 16 + q * 4 + r) * 68 + 48 + n] = macc3[r];
    }
    __syncthreads();   // B4

    const int x   = xt * PIX + lane;
    const int pix = y * W_ + x;
    float u = umv[lane];
    float* ob = out + ((size_t)b * COUT + w * 16) * HW_ + pix;
    const float* bs = bias + w * 16;
    const float* dp = &dout[lane * 68 + w * 16];
    #pragma unroll
    for (int o = 0; o < 16; ++o)
        ob[(size_t)o * HW_] = (dp[o] + bs[o]) * u;
}

// ---------------------------------------------------------------------------
extern "C" void kernel_launch(void* const* d_in, const int* in_sizes, int n_in,
                              void* d_out, int out_size, void* d_ws, size_t ws_size,
                              hipStream_t stream) {
    const float* input   = (const float*)d_in[0];
    const float* mask_in = (const float*)d_in[1];
    const float* weight  = (const float*)d_in[2];
    const float* bias    = (const float*)d_in[3];
    const float* sem_w   = (const float*)d_in[4];
    const float* sem_b   = (const float*)d_in[5];
    const float* reg_w   = (const float*)d_in[6];
    const float* reg_b   = (const float*)d_in[7];
    const float* m1_w    = (const float*)d_in[8];
    const float* m1_b    = (const float*)d_in[9];
    const float* m2_w    = (const float*)d_in[10];
    const float* m2_b    = (const float*)d_in[11];

    float* out = (float*)d_out;                        // (B,COUT,H,W)
    float* um  = out + (size_t)B_ * COUT * HW_;        // (B,1,H,W)

    // workspace (shorts): inpT (9.44 MB) + wbm + wbs  ≈ 9.55 MB total
    short* inpT = (short*)d_ws;                        // B*HW*64
    short* wbm  = inpT + (size_t)B_ * HW_ * 64;        // 36,864
    short* wbs  = wbm + 18 * 4 * 64 * 8;               // 18,432

    const int blk = 256;
    const int nblocks = B_ * H_ * XT_;                 // 1152

    nhwc_kernel<<<B_ * (HW_ / 64), blk, 0, stream>>>(input, inpT);
    wtrans_kernel<<<(18 * 4 * 64 * 8 + 18 * 2 * 64 * 8 + blk - 1) / blk, blk, 0, stream>>>(
        weight, sem_w, m2_w, wbm, wbs);
    fused_kernel<<<nblocks, blk, 0, stream>>>(
        inpT, mask_in, wbs, wbm, sem_b, reg_w, reg_b, m1_w, m1_b, m2_b,
        bias, out, um);
}

// Round 9
// 163.402 us; speedup vs baseline: 2.9340x; 1.0044x over previous
//
#include <hip/hip_runtime.h>
#include <hip/hip_bf16.h>
#include <math.h>

#define B_  2
#define CIN 64
#define COUT 64
#define H_  192
#define W_  192
#define G_  2
#define KK_ 9
#define CG_ 32
#define HW_ (H_*W_)
#define PIX 64            // pixels per block (x-contiguous)
#define XT_ (W_/PIX)      // 3 x-tiles per row

typedef __attribute__((ext_vector_type(8))) short bf16x8;
typedef __attribute__((ext_vector_type(4))) float f32x4;

// round-to-nearest-even fp32 -> bf16 bit pattern (scalar fallback path)
static __device__ __forceinline__ short f2bf(float f) {
    unsigned u = __builtin_bit_cast(unsigned, f);
    u = (u + 0x7fffu + ((u >> 16) & 1u)) >> 16;
    return (short)u;
}
static __device__ __forceinline__ float bf2f(short s) {
    unsigned u = ((unsigned)(unsigned short)s) << 16;
    return __builtin_bit_cast(float, u);
}
// packed fp32x2 -> bf16x2 (v_cvt_pk_bf16_f32 on gfx950)
static __device__ __forceinline__ short2 pk2bf(float lo, float hi) {
    float2 f; f.x = lo; f.y = hi;
    __hip_bfloat162 hh = __float22bfloat162_rn(f);
    short2 r;
    __builtin_memcpy(&r, &hh, sizeof(r));
    return r;
}

// ---------------------------------------------------------------------------
// Kernel A: NCHW fp32 -> NHWC bf16 transform. 16-B stores.
// ---------------------------------------------------------------------------
__global__ __launch_bounds__(256)
void nhwc_kernel(const float* __restrict__ in, short* __restrict__ inpT) {
    __shared__ float t[64][65];
    const int tid = threadIdx.x;
    const int bid = blockIdx.x;                 // B * (HW/64) = 1152
    const int b = bid / (HW_ / 64);
    const int pix0 = (bid % (HW_ / 64)) * 64;
    const float* src = in + (size_t)b * CIN * HW_ + pix0;
    const int c0 = (tid >> 6) * 16;
    const int p  = tid & 63;
    #pragma unroll
    for (int i = 0; i < 16; ++i)
        t[c0 + i][p] = src[(size_t)(c0 + i) * HW_ + p];
    __syncthreads();
    short* dst = inpT + ((size_t)b * HW_ + pix0) * 64;
    #pragma unroll
    for (int i = 0; i < 2; ++i) {
        int item = i * 256 + tid;
        int pp = item >> 3, oct = item & 7;
        bf16x8 v;
        #pragma unroll
        for (int j = 0; j < 8; j += 2) {
            short2 ss = pk2bf(t[oct * 8 + j][pp], t[oct * 8 + j + 1][pp]);
            v[j] = ss.x; v[j + 1] = ss.y;
        }
        *(bf16x8*)&dst[pp * 64 + oct * 8] = v;
    }
}

// ---------------------------------------------------------------------------
// Kernel B: pack weights into MFMA B-fragment order (bf16). (r6-verified)
// ---------------------------------------------------------------------------
__global__ void wtrans_kernel(const float* __restrict__ weight,
                              const float* __restrict__ sem_w,
                              const float* __restrict__ m2_w,
                              short* __restrict__ wbm,
                              short* __restrict__ wbs) {
    int i = blockIdx.x * blockDim.x + threadIdx.x;
    if (i < 18 * 4 * 64 * 8) {
        int j = i & 7, lane = (i >> 3) & 63, nt = (i >> 9) & 3, gk = i >> 11;
        int n = lane & 15, q = lane >> 4;
        int o = nt * 16 + n;
        int g = gk / 9, k = gk - g * 9;
        int cin = g * CG_ + q * 8 + j;
        wbm[i] = f2bf(weight[(o * CIN + cin) * 9 + k]);
        return;
    }
    int ii = i - 18 * 4 * 64 * 8;
    if (ii >= 18 * 2 * 64 * 8) return;
    int j = ii & 7, lane = (ii >> 3) & 63, nt = (ii >> 9) & 1, s = ii >> 10;
    int t = s >> 1, h = s & 1;
    int n = lane & 15, q = lane >> 4;
    int o = nt * 16 + n;
    int c = h * 32 + q * 8 + j;
    float v = 0.f;
    if (o < 18)      v = sem_w[(o * CIN + c) * 9 + t];
    else if (o < 27) v = m2_w[((o - 18) * CIN + c) * 9 + t];
    wbs[ii] = f2bf(v);
}

// ---------------------------------------------------------------------------
// one main-conv K-step (gk in [0,18), GOFF = channel-group offset 0 or 32)
// NAMED accumulators macc0..macc3 — do not convert to an array (miscompiles).
// ---------------------------------------------------------------------------
#define MBODY(GK, GOFF) { \
    float2 XY = pxy[(GK) * 64 + w * 16 + n]; \
    float dm  = dml[(GK) * 64 + w * 16 + n]; \
    float Y = XY.x, X = XY.y; \
    float y0f = floorf(Y), x0f = floorf(X); \
    int y0 = (int)y0f, x0 = (int)x0f; \
    float ly = Y - y0f, lx = X - x0f; \
    int y1 = y0 + 1, x1 = x0 + 1; \
    bool vy0 = (y0 >= 0 && y0 < H_), vy1 = (y1 >= 0 && y1 < H_); \
    bool vx0 = (x0 >= 0 && x0 < W_), vx1 = (x1 >= 0 && x1 < W_); \
    float w00 = (vy0 && vx0) ? (1.f - ly) * (1.f - lx) * dm : 0.f; \
    float w01 = (vy0 && vx1) ? (1.f - ly) * lx * dm : 0.f; \
    float w10 = (vy1 && vx0) ? ly * (1.f - lx) * dm : 0.f; \
    float w11 = (vy1 && vx1) ? ly * lx * dm : 0.f; \
    int yc0 = min(max(y0, 0), H_ - 1), yc1 = min(max(y1, 0), H_ - 1); \
    int xc0 = min(max(x0, 0), W_ - 1), xc1 = min(max(x1, 0), W_ - 1); \
    const short* pb = inpT + (size_t)b * HW_ * 64 + (GOFF) + q * 8; \
    bf16x8 c00 = *(const bf16x8*)(pb + (size_t)(yc0 * W_ + xc0) * 64); \
    bf16x8 c01 = *(const bf16x8*)(pb + (size_t)(yc0 * W_ + xc1) * 64); \
    bf16x8 c10 = *(const bf16x8*)(pb + (size_t)(yc1 * W_ + xc0) * 64); \
    bf16x8 c11 = *(const bf16x8*)(pb + (size_t)(yc1 * W_ + xc1) * 64); \
    bf16x8 a; \
    _Pragma("unroll") \
    for (int j = 0; j < 8; j += 2) { \
        float s0 = w00 * bf2f(c00[j])   + w01 * bf2f(c01[j]) \
                 + w10 * bf2f(c10[j])   + w11 * bf2f(c11[j]); \
        float s1 = w00 * bf2f(c00[j+1]) + w01 * bf2f(c01[j+1]) \
                 + w10 * bf2f(c10[j+1]) + w11 * bf2f(c11[j+1]); \
        short2 ss = pk2bf(s0, s1); \
        a[j] = ss.x; a[j + 1] = ss.y; \
    } \
    bf16x8 wb0 = ((const bf16x8*)wbm)[((GK) * 4 + 0) * 64 + lane]; \
    bf16x8 wb1 = ((const bf16x8*)wbm)[((GK) * 4 + 1) * 64 + lane]; \
    bf16x8 wb2 = ((const bf16x8*)wbm)[((GK) * 4 + 2) * 64 + lane]; \
    bf16x8 wb3 = ((const bf16x8*)wbm)[((GK) * 4 + 3) * 64 + lane]; \
    macc0 = __builtin_amdgcn_mfma_f32_16x16x32_bf16(a, wb0, macc0, 0, 0, 0); \
    macc1 = __builtin_amdgcn_mfma_f32_16x16x32_bf16(a, wb1, macc1, 0, 0, 0); \
    macc2 = __builtin_amdgcn_mfma_f32_16x16x32_bf16(a, wb2, macc2, 0, 0, 0); \
    macc3 = __builtin_amdgcn_mfma_f32_16x16x32_bf16(a, wb3, macc3, 0, 0, 0); \
}

// ---------------------------------------------------------------------------
// Kernel C: fully fused — offsets (MFMA) + modulation + umask + main conv.
// ---------------------------------------------------------------------------
__global__ __launch_bounds__(256)
void fused_kernel(const short* __restrict__ inpT,
                  const float* __restrict__ mask_in,
                  const short* __restrict__ wbs,
                  const short* __restrict__ wbm,
                  const float* __restrict__ sem_b,
                  const float* __restrict__ reg_w, const float* __restrict__ reg_b,
                  const float* __restrict__ m1_w, const float* __restrict__ m1_b,
                  const float* __restrict__ m2_b,
                  const float* __restrict__ bias,
                  float* __restrict__ out, float* __restrict__ um_out) {
    __shared__ __align__(16) char sh[17408];   // red[64][36]+ums | dout[64][68]
    float* red  = (float*)sh;
    float* ums  = (float*)(sh + 9216);
    float* dout = (float*)sh;
    __shared__ float2 pxy[18 * 64];            // (py, px) per (gk, pixel)
    __shared__ float  dml[18 * 64];
    __shared__ float  umv[64];

    const int tid  = threadIdx.x;
    const int lane = tid & 63;
    const int w    = __builtin_amdgcn_readfirstlane(tid >> 6);
    const int n = lane & 15, q = lane >> 4;

    // XCD band swizzle: band = bid&7 -> contiguous 48-row y-band per XCD
    const int bid  = blockIdx.x;
    const int band = bid & 7;
    const int jb   = bid >> 3;                 // 0..143
    const int xt   = jb % 3;
    const int rr   = band * 48 + jb / 3;       // global row in [0, 384)
    const int y    = rr % H_;
    const int b    = rr / H_;

    const int xn = xt * PIX + w * 16 + n;      // fragment pixel (M-row)

    // ================= phase O: sem(18)+m2(9) conv via MFMA =================
    f32x4 acc0 = {0.f, 0.f, 0.f, 0.f}, acc1 = {0.f, 0.f, 0.f, 0.f};
    #pragma unroll 2
    for (int s = 0; s < 18; ++s) {
        int t_ = s >> 1, h = s & 1;
        int dy = t_ / 3 - 1, dx = t_ % 3 - 1;
        int yy = y + dy, xx = xn + dx;
        bool vv = (yy >= 0 && yy < H_ && xx >= 0 && xx < W_);
        int yc = min(max(yy, 0), H_ - 1), xc = min(max(xx, 0), W_ - 1);
        bf16x8 a = *(const bf16x8*)&inpT[((size_t)(b * HW_ + yc * W_ + xc)) * 64 + h * 32 + q * 8];
        if (!vv) { a[0]=0;a[1]=0;a[2]=0;a[3]=0;a[4]=0;a[5]=0;a[6]=0;a[7]=0; }
        bf16x8 b0 = ((const bf16x8*)wbs)[(s * 2 + 0) * 64 + lane];
        bf16x8 b1 = ((const bf16x8*)wbs)[(s * 2 + 1) * 64 + lane];
        acc0 = __builtin_amdgcn_mfma_f32_16x16x32_bf16(a, b0, acc0, 0, 0, 0);
        acc1 = __builtin_amdgcn_mfma_f32_16x16x32_bf16(a, b1, acc1, 0, 0, 0);
    }
    #pragma unroll
    for (int r = 0; r < 4; ++r) {
        red[(w * 16 + q * 4 + r) * 36 + n]      = acc0[r];
        red[(w * 16 + q * 4 + r) * 36 + 16 + n] = acc1[r];
    }
    __syncthreads();   // B1

    // ================= phase 3: finish offsets/modulation/umask =============
    {
        const int xl = xt * PIX + lane;
        const int pixl = y * W_ + xl;
        const bool vxm = xl > 0, vxp = (xl + 1) < W_;
        const bool vym = y > 0,  vyp = (y + 1) < H_;
        int g  = w >> 1;
        int k0 = (w & 1) ? 5 : 0;
        int k1 = (w & 1) ? 9 : 5;
        float off_[18], mm[9];
        if (g == 0) {
            const float* mbp = mask_in + (size_t)b * HW_ + pixl;
            float mv[9];
            mv[0] = (vym && vxm) ? mbp[-W_ - 1] : 0.f;
            mv[1] = vym ? mbp[-W_] : 0.f;
            mv[2] = (vym && vxp) ? mbp[-W_ + 1] : 0.f;
            mv[3] = vxm ? mbp[-1] : 0.f;
            mv[4] = mbp[0];
            mv[5] = vxp ? mbp[1] : 0.f;
            mv[6] = (vyp && vxm) ? mbp[W_ - 1] : 0.f;
            mv[7] = vyp ? mbp[W_] : 0.f;
            mv[8] = (vyp && vxp) ? mbp[W_ + 1] : 0.f;
            #pragma unroll
            for (int o = 0; o < 18; ++o) off_[o] = reg_b[o];
            #pragma unroll
            for (int o = 0; o < 9; ++o) mm[o] = m1_b[o];
            #pragma unroll
            for (int t = 0; t < 9; ++t) {
                float vt = mv[t];
                #pragma unroll
                for (int o = 0; o < 18; ++o) off_[o] += vt * reg_w[o * 9 + t];
                #pragma unroll
                for (int o = 0; o < 9; ++o) mm[o] += vt * m1_w[o * 9 + t];
            }
        } else {
            #pragma unroll
            for (int o = 0; o < 18; ++o) off_[o] = red[lane * 36 + o] + sem_b[o];
            #pragma unroll
            for (int o = 0; o < 9; ++o) mm[o] = red[lane * 36 + 18 + o] + m2_b[o];
        }

        const float* mb = mask_in + (size_t)b * HW_;
        float s_um = 0.f;
        #pragma unroll
        for (int k = 0; k < 9; ++k) {
            if (k < k0 || k >= k1) continue;
            float Y = off_[2 * k]     + (float)y  + (float)(k / 3 - 1);
            float X = off_[2 * k + 1] + (float)xl + (float)(k % 3 - 1);
            int gk = g * 9 + k;
            float2 xy; xy.x = Y; xy.y = X;
            pxy[gk * 64 + lane] = xy;
            dml[gk * 64 + lane] = 1.f / (1.f + expf(-mm[k]));
            float y0f = floorf(Y), x0f = floorf(X);
            int y0 = (int)y0f, x0 = (int)x0f;
            float ly = Y - y0f, lx = X - x0f;
            int y1 = y0 + 1, x1 = x0 + 1;
            bool vy0 = (y0 >= 0 && y0 < H_), vy1 = (y1 >= 0 && y1 < H_);
            bool vx0 = (x0 >= 0 && x0 < W_), vx1 = (x1 >= 0 && x1 < W_);
            int yc0 = min(max(y0, 0), H_ - 1), yc1 = min(max(y1, 0), H_ - 1);
            int xc0 = min(max(x0, 0), W_ - 1), xc1 = min(max(x1, 0), W_ - 1);
            float v00 = (vy0 && vx0) ? mb[yc0 * W_ + xc0] : 0.f;
            float v01 = (vy0 && vx1) ? mb[yc0 * W_ + xc1] : 0.f;
            float v10 = (vy1 && vx0) ? mb[yc1 * W_ + xc0] : 0.f;
            float v11 = (vy1 && vx1) ? mb[yc1 * W_ + xc1] : 0.f;
            s_um += v00 * (1.f - ly) * (1.f - lx) + v01 * (1.f - ly) * lx
                  + v10 * ly * (1.f - lx)        + v11 * ly * lx;
        }
        ums[w * 64 + lane] = s_um;
    }
    __syncthreads();   // B2
    if (w == 0) {
        float s = ums[lane] + ums[64 + lane] + ums[128 + lane] + ums[192 + lane];
        float u = fminf(fmaxf(64.f * s, 0.f), 1.f);
        um_out[(size_t)b * HW_ + y * W_ + xt * PIX + lane] = u;
        umv[lane] = u;
    }
    __syncthreads();   // B3

    // ================= phase M: main deformable conv via MFMA ===============
    f32x4 macc0 = {0.f, 0.f, 0.f, 0.f};
    f32x4 macc1 = {0.f, 0.f, 0.f, 0.f};
    f32x4 macc2 = {0.f, 0.f, 0.f, 0.f};
    f32x4 macc3 = {0.f, 0.f, 0.f, 0.f};

    for (int kk = 0; kk < KK_; ++kk) {
        MBODY(kk, 0)            // group 0, channels 0..31
        MBODY(kk + 9, CG_)      // group 1, channels 32..63
    }

    // epilogue: D -> LDS transpose -> coalesced stores
    #pragma unroll
    for (int r = 0; r < 4; ++r) {
        dout[(w * 16 + q * 4 + r) * 68 +  0 + n] = macc0[r];
        dout[(w * 16 + q * 4 + r) * 68 + 16 + n] = macc1[r];
        dout[(w * 16 + q * 4 + r) * 68 + 32 + n] = macc2[r];
        dout[(w * 16 + q * 4 + r) * 68 + 48 + n] = macc3[r];
    }
    __syncthreads();   // B4

    const int x   = xt * PIX + lane;
    const int pix = y * W_ + x;
    float u = umv[lane];
    float* ob = out + ((size_t)b * COUT + w * 16) * HW_ + pix;
    const float* bs = bias + w * 16;
    const float* dp = &dout[lane * 68 + w * 16];
    #pragma unroll
    for (int o = 0; o < 16; ++o)
        ob[(size_t)o * HW_] = (dp[o] + bs[o]) * u;
}

// ---------------------------------------------------------------------------
extern "C" void kernel_launch(void* const* d_in, const int* in_sizes, int n_in,
                              void* d_out, int out_size, void* d_ws, size_t ws_size,
                              hipStream_t stream) {
    const float* input   = (const float*)d_in[0];
    const float* mask_in = (const float*)d_in[1];
    const float* weight  = (const float*)d_in[2];
    const float* bias    = (const float*)d_in[3];
    const float* sem_w   = (const float*)d_in[4];
    const float* sem_b   = (const float*)d_in[5];
    const float* reg_w   = (const float*)d_in[6];
    const float* reg_b   = (const float*)d_in[7];
    const float* m1_w    = (const float*)d_in[8];
    const float* m1_b    = (const float*)d_in[9];
    const float* m2_w    = (const float*)d_in[10];
    const float* m2_b    = (const float*)d_in[11];

    float* out = (float*)d_out;                        // (B,COUT,H,W)
    float* um  = out + (size_t)B_ * COUT * HW_;        // (B,1,H,W)

    // workspace (shorts): inpT (9.44 MB) + wbm + wbs
    short* inpT = (short*)d_ws;                        // B*HW*64
    short* wbm  = inpT + (size_t)B_ * HW_ * 64;        // 36,864
    short* wbs  = wbm + 18 * 4 * 64 * 8;               // 18,432

    const int blk = 256;
    const int nblocks = B_ * H_ * XT_;                 // 1152

    nhwc_kernel<<<B_ * (HW_ / 64), blk, 0, stream>>>(input, inpT);
    wtrans_kernel<<<(18 * 4 * 64 * 8 + 18 * 2 * 64 * 8 + blk - 1) / blk, blk, 0, stream>>>(
        weight, sem_w, m2_w, wbm, wbs);
    fused_kernel<<<nblocks, blk, 0, stream>>>(
        inpT, mask_in, wbs, wbm, sem_b, reg_w, reg_b, m1_w, m1_b, m2_b,
        bias, out, um);
}